// Round 17
// baseline (94.746 us; speedup 1.0000x reference)
//
#include <hip/hip_runtime.h>
#include <hip/hip_bf16.h>

typedef __bf16 bf16_t;
typedef __bf16 bf16x4 __attribute__((ext_vector_type(4)));
typedef __bf16 bf16x8 __attribute__((ext_vector_type(8)));
typedef float f32x4 __attribute__((ext_vector_type(4)));

#define B_ 2
#define T_ 2048
#define C_ 1024
#define H_ 16
#define HD_ 64
#define RD_ 32
#define M_ (B_ * T_)  // 4096

// ---------------- prep: transpose/cvt both W (x-cvt now fused into k_gemm1) ----------------
__global__ __launch_bounds__(256) void k_prep(const float* __restrict__ Wq,
                                              bf16_t* __restrict__ wqt,
                                              const float* __restrict__ Wp,
                                              bf16_t* __restrict__ wpt) {
    __shared__ float tile[32][33];
    int b2 = blockIdx.x;
    const float* W = (b2 < 1024) ? Wq : Wp;
    bf16_t* Wt = (b2 < 1024) ? wqt : wpt;
    b2 &= 1023;
    const int n0 = (b2 & 31) * 32, k0 = (b2 >> 5) * 32;
    const int tx = threadIdx.x & 31, ty = threadIdx.x >> 5;
    for (int i = ty; i < 32; i += 8)
        tile[i][tx] = W[(size_t)(k0 + i) * C_ + n0 + tx];
    __syncthreads();
    for (int i = ty; i < 32; i += 8)
        Wt[(size_t)(n0 + i) * C_ + k0 + tx] = (bf16_t)tile[tx][i];
}

// ---------------- GEMM1 (fused): qp/vp = rope+rms(x @ Wqkv) ----------------
// A read DIRECTLY from x (fp32): reg-staged (8 f32x4 -> cvt -> 4 swizzled
// ds_write_b128), dist-1 double-buffer, issue-early/write-late (T14). B via
// global_load_lds, 3-buffer dist-2. Counted vmcnt(2): FIFO guarantees
// A(kt+1)+B(kt+1) landed while B(kt+2) stays in flight. Kills the 24MB
// x->xb round-trip. XCD-affine (bx=head group matches attn's reader XCD).
__global__ __launch_bounds__(256) void k_gemm1(const float* __restrict__ x,
                                               const bf16_t* __restrict__ Bt,
                                               const float* __restrict__ ct,
                                               const float* __restrict__ st,
                                               bf16_t* __restrict__ qp,
                                               bf16_t* __restrict__ vp) {
    __shared__ __align__(16) char smem[57344];   // As 2x16KB + Bs 3x8KB = 56KB
    bf16_t* As = (bf16_t*)smem;                  // [2][128*64]
    bf16_t* Bs = (bf16_t*)(smem + 32768);        // [3][64*64]
    const int K = C_;
    const int tid = threadIdx.x;
    const int lane = tid & 63, w = tid >> 6;
    const int wr = w >> 1, wc = w & 1;
    const int g = lane >> 4, li = lane & 15;
    const int bid = blockIdx.x;
    const int xcd = bid & 7, i0 = bid >> 3;      // 64 tiles per XCD
    const int bx = (xcd & 3) * 4 + (i0 & 3);     // head
    const int by = (xcd >> 2) * 16 + (i0 >> 2);  // M block
    const size_t rowA0 = (size_t)by * 128;
    const size_t colB0 = (size_t)bx * 64;
    const float* Ab = x + rowA0 * K;
    const bf16_t* Bb = Bt + colB0 * K;
    f32x4 acc[4][2] = {};

    const int lr = lane >> 3;
    const int swc = ((lane & 7) ^ lr) * 8;       // B pre-swizzled source col

    // A staging map: row = tid>>1 (0..127), half = tid&1 (k 0 or 32)
    const int arow = tid >> 1, ahalf = tid & 1;

    auto stageB = [&](int buf, int k0) {
        bf16_t* Bd = Bs + buf * 4096 + (w * 8) * 64;
#pragma unroll
        for (int bq = 0; bq < 2; ++bq) {
            const bf16_t* src = Bb + (size_t)(bq * 32 + w * 8 + lr) * K + k0 + swc;
            __builtin_amdgcn_global_load_lds(
                (const __attribute__((address_space(1))) void*)src,
                (__attribute__((address_space(3))) void*)(Bd + bq * 32 * 64), 16, 0, 0);
        }
    };
    auto loadA = [&](int k0, f32x4* ar) {
        const float* src = Ab + (size_t)arow * K + k0 + ahalf * 32;
#pragma unroll
        for (int c = 0; c < 8; ++c) ar[c] = ((const f32x4*)src)[c];
    };
    auto writeA = [&](int buf, const f32x4* ar) {
        bf16_t* base = As + buf * 8192 + arow * 64;
#pragma unroll
        for (int c = 0; c < 4; ++c) {          // chunk gc = ahalf*4+c (8 bf16)
            bf16x8 ch;
#pragma unroll
            for (int e = 0; e < 4; ++e) {
                ch[e]     = (bf16_t)ar[c * 2][e];
                ch[e + 4] = (bf16_t)ar[c * 2 + 1][e];
            }
            const int gc = ahalf * 4 + c;
            *(bf16x8*)(base + ((gc ^ (arow & 7)) * 8)) = ch;
        }
    };

    const int NT = K >> 6;                       // 16
    f32x4 ar[8];
    loadA(0, ar);
    stageB(0, 0);
    stageB(1, 64);
    asm volatile("s_waitcnt vmcnt(2)" ::: "memory");   // A(0)+B(0) landed
    writeA(0, ar);
    asm volatile("s_waitcnt lgkmcnt(0)" ::: "memory");
    __builtin_amdgcn_s_barrier();

    for (int kt = 0; kt < NT; ++kt) {
        if (kt + 1 < NT) loadA((kt + 1) << 6, ar);
        if (kt + 2 < NT) stageB((kt + 2) % 3, (kt + 2) << 6);
        const int ca = kt & 1, cb = kt % 3;
        bf16x8 af[4][2], bfr[2][2];
#pragma unroll
        for (int i = 0; i < 4; ++i) {
            const int row = wr * 64 + i * 16 + li;
#pragma unroll
            for (int kk = 0; kk < 2; ++kk)
                af[i][kk] = *(const bf16x8*)(As + ca * 8192 + row * 64 +
                                             (((kk * 4 + g) ^ (row & 7)) * 8));
        }
#pragma unroll
        for (int j = 0; j < 2; ++j) {
            const int row = wc * 32 + j * 16 + li;
#pragma unroll
            for (int kk = 0; kk < 2; ++kk)
                bfr[j][kk] = *(const bf16x8*)(Bs + cb * 4096 + row * 64 +
                                              (((kk * 4 + g) ^ (row & 7)) * 8));
        }
#pragma unroll
        for (int i = 0; i < 4; ++i)
#pragma unroll
            for (int j = 0; j < 2; ++j)
#pragma unroll
                for (int kk = 0; kk < 2; ++kk)
                    acc[i][j] = __builtin_amdgcn_mfma_f32_16x16x32_bf16(
                        af[i][kk], bfr[j][kk], acc[i][j], 0, 0, 0);
        if (kt + 1 < NT) {
            if (kt + 2 < NT)
                asm volatile("s_waitcnt vmcnt(2)" ::: "memory");  // A(kt+1)+B(kt+1) done
            else
                asm volatile("s_waitcnt vmcnt(0)" ::: "memory");
            writeA((kt + 1) & 1, ar);
        }
        asm volatile("s_waitcnt lgkmcnt(0)" ::: "memory");
        __builtin_amdgcn_s_barrier();
    }

    // ---- fused RoPE + RMS epilogue (head = bx, 128 t-rows in one b) ----
    float* ot = (float*)smem;                   // [128][68] fp32
    bf16_t* qs = (bf16_t*)(smem + 34816);       // [64][136] bf16 (d-major)
#pragma unroll
    for (int i = 0; i < 4; ++i)
#pragma unroll
        for (int j = 0; j < 2; ++j)
#pragma unroll
            for (int r = 0; r < 4; ++r)
                ot[(wr * 64 + i * 16 + g * 4 + r) * 68 + wc * 32 + j * 16 + li] =
                    acc[i][j][r];
    __syncthreads();
    const int bb = (int)(rowA0 >> 11);
    {
        const int row = tid >> 1, half = tid & 1;  // 2 threads per t-row
        const int t = ((int)rowA0 + row) & 2047;
        const float* own = ot + row * 68 + half * 32;
        const float* par = ot + row * 68 + (half ^ 1) * 32;
        const float* cp = ct + (size_t)t * RD_;
        const float* sp = st + (size_t)t * RD_;
        float y[32];
        float sq = 0.f;
#pragma unroll
        for (int c4 = 0; c4 < 8; ++c4) {
            float4 xo = ((const float4*)own)[c4];
            float4 xp = ((const float4*)par)[c4];
            float4 cc = ((const float4*)cp)[c4];
            float4 ss = ((const float4*)sp)[c4];
            float* yy = y + c4 * 4;
            if (half == 0) {
                yy[0] = xo.x * cc.x + xp.x * ss.x;
                yy[1] = xo.y * cc.y + xp.y * ss.y;
                yy[2] = xo.z * cc.z + xp.z * ss.z;
                yy[3] = xo.w * cc.w + xp.w * ss.w;
            } else {
                yy[0] = xo.x * cc.x - xp.x * ss.x;
                yy[1] = xo.y * cc.y - xp.y * ss.y;
                yy[2] = xo.z * cc.z - xp.z * ss.z;
                yy[3] = xo.w * cc.w - xp.w * ss.w;
            }
            sq += yy[0] * yy[0] + yy[1] * yy[1] + yy[2] * yy[2] + yy[3] * yy[3];
        }
        sq += __shfl_xor(sq, 1);
        const float rn = rsqrtf(sq * (1.0f / 64.0f) + 1.1920929e-7f);
        bf16_t yb[32];
#pragma unroll
        for (int e = 0; e < 32; ++e) yb[e] = (bf16_t)(y[e] * rn);
        bf16_t* qpb = qp + ((size_t)(bb * H_ + bx) * 128 + (t >> 4)) * 1024;
#pragma unroll
        for (int c8 = 0; c8 < 4; ++c8) {
            const int chunk = (half * 4 + c8) * 16 + (t & 15);
            *(bf16x8*)(qpb + chunk * 8) = *(const bf16x8*)(yb + c8 * 8);
        }
#pragma unroll
        for (int e = 0; e < 32; ++e)
            qs[(half * 32 + e) * 136 + row] = yb[e];
    }
    __syncthreads();
    {
        const int d = tid >> 2, jc4 = tid & 3;
        const int tt0 = (int)((rowA0 & 2047) >> 6);
        bf16_t* vpb = vp + ((size_t)(bb * H_ + bx) * 32) * 4096;
#pragma unroll
        for (int c = 0; c < 4; ++c) {
            const int jc = jc4 * 4 + c;               // 0..15 (j-chunk of 8)
            bf16x8 v8 = *(const bf16x8*)(qs + d * 136 + jc * 8);
            bf16_t* dst = vpb + (size_t)(tt0 + (jc >> 3)) * 4096 +
                          ((d >> 4) * 8 + (jc & 7)) * 128 + (d & 15) * 8;
            *(bf16x8*)dst = v8;
        }
    }
}

// ---------------- GEMM2: out = ao @ Wproj (identical to round 16) ----------------
__global__ __launch_bounds__(256) void k_gemm2(const bf16_t* __restrict__ A,
                                               const bf16_t* __restrict__ Bt,
                                               float* __restrict__ C) {
    __shared__ __align__(16) char smem[73728];   // 3 bufs
    bf16_t* As = (bf16_t*)smem;                  // [3][128*64]
    bf16_t* Bs = (bf16_t*)(smem + 49152);        // [3][64*64]
    const int K = C_, N = C_;
    const int tid = threadIdx.x;
    const int lane = tid & 63, w = tid >> 6;
    const int wr = w >> 1, wc = w & 1;
    const int g = lane >> 4, li = lane & 15;
    const int bid = blockIdx.x;
    const int work = (bid & 7) * 64 + (bid >> 3);  // bijective for 512
    const int bx = work & 15;
    const int by = work >> 4;
    const size_t rowA0 = (size_t)by * 128;
    const size_t colB0 = (size_t)bx * 64;
    const bf16_t* Ab = A + rowA0 * K;
    const bf16_t* Bb = Bt + colB0 * K;
    f32x4 acc[4][2] = {};

    const int lr = lane >> 3;
    const int swc = ((lane & 7) ^ lr) * 8;

    auto stage = [&](int buf, int k0) {
        bf16_t* Ad = As + buf * 8192 + (w * 8) * 64;
        bf16_t* Bd = Bs + buf * 4096 + (w * 8) * 64;
#pragma unroll
        for (int a = 0; a < 4; ++a) {
            const bf16_t* src = Ab + (size_t)(a * 32 + w * 8 + lr) * K + k0 + swc;
            __builtin_amdgcn_global_load_lds(
                (const __attribute__((address_space(1))) void*)src,
                (__attribute__((address_space(3))) void*)(Ad + a * 32 * 64), 16, 0, 0);
        }
#pragma unroll
        for (int bq = 0; bq < 2; ++bq) {
            const bf16_t* src = Bb + (size_t)(bq * 32 + w * 8 + lr) * K + k0 + swc;
            __builtin_amdgcn_global_load_lds(
                (const __attribute__((address_space(1))) void*)src,
                (__attribute__((address_space(3))) void*)(Bd + bq * 32 * 64), 16, 0, 0);
        }
    };

    const int NT = K >> 6;                    // 16
    stage(0, 0);
    stage(1, 64);
    for (int kt = 0; kt < NT; ++kt) {
        if (kt + 1 < NT)
            asm volatile("s_waitcnt vmcnt(6)" ::: "memory");
        else
            asm volatile("s_waitcnt vmcnt(0)" ::: "memory");
        __builtin_amdgcn_s_barrier();
        if (kt + 2 < NT) stage((kt + 2) % 3, (kt + 2) << 6);
        const int cb = kt % 3;
        bf16x8 af[4][2], bfr[2][2];
#pragma unroll
        for (int i = 0; i < 4; ++i) {
            const int row = wr * 64 + i * 16 + li;
#pragma unroll
            for (int kk = 0; kk < 2; ++kk)
                af[i][kk] = *(const bf16x8*)(As + cb * 8192 + row * 64 +
                                             (((kk * 4 + g) ^ (row & 7)) * 8));
        }
#pragma unroll
        for (int j = 0; j < 2; ++j) {
            const int row = wc * 32 + j * 16 + li;
#pragma unroll
            for (int kk = 0; kk < 2; ++kk)
                bfr[j][kk] = *(const bf16x8*)(Bs + cb * 4096 + row * 64 +
                                              (((kk * 4 + g) ^ (row & 7)) * 8));
        }
#pragma unroll
        for (int i = 0; i < 4; ++i)
#pragma unroll
            for (int j = 0; j < 2; ++j)
#pragma unroll
                for (int kk = 0; kk < 2; ++kk)
                    acc[i][j] = __builtin_amdgcn_mfma_f32_16x16x32_bf16(
                        af[i][kk], bfr[j][kk], acc[i][j], 0, 0, 0);
    }
#pragma unroll
    for (int i = 0; i < 4; ++i)
#pragma unroll
        for (int j = 0; j < 2; ++j)
#pragma unroll
            for (int r = 0; r < 4; ++r) {
                size_t row = rowA0 + wr * 64 + i * 16 + g * 4 + r;
                size_t col = colB0 + wc * 32 + j * 16 + li;
                C[row * N + col] = acc[i][j][r];
            }
}

// ---------------- flash attention (identical to round 12) ----------------
__global__ __launch_bounds__(256, 2) void k_attn(const bf16_t* __restrict__ qp,
                                                 const bf16_t* __restrict__ vp,
                                                 bf16_t* __restrict__ aout,
                                                 const int* __restrict__ wlp) {
    __shared__ bf16_t pb[4][16][40];
    const int tid = threadIdx.x;
    const int lane = tid & 63, w = tid >> 6;
    const int g = lane >> 4, li = lane & 15;
    const int bid = blockIdx.x;
    const int work = (bid & 7) * 128 + (bid >> 3);
    const int tb = work & 31;
    const int h = (work >> 5) & 15;
    const int b = work >> 9;
    const int Q0 = tb * 64;
    const bf16_t* bq = qp + (size_t)(b * H_ + h) * 131072;
    const bf16_t* bv = vp + (size_t)(b * H_ + h) * 131072;
    const int wl = wlp[0];
    const int wle = (wl <= 0 || wl > T_) ? T_ : wl;
    const int qw = Q0 + w * 16;
    const int qg = qw + li;

    const int fo = (g * 16 + li) * 8;
    const int vo = g * 128 + li * 8;

    bf16x8 aq[2];
    aq[0] = *(const bf16x8*)(bq + (size_t)(qw >> 4) * 1024 + fo);
    aq[1] = *(const bf16x8*)(bq + (size_t)(qw >> 4) * 1024 + fo + 512);

    f32x4 o[4] = {};
    float m = -1e30f, l = 0.f;
    const float SC = 0.125f * 1.44269504089f;

    const int kb0 = (qw > wle) ? ((qw - wle) >> 6) : 0;
    const int kb1 = qw >> 6;

    for (int kb = kb0; kb <= kb1; ++kb) {
        const int J0 = kb << 6;
        const bf16_t* kt = bq + (size_t)kb * 4096;
        const bf16_t* vt = bv + (size_t)kb * 4096;
        bf16x8 kf[2][4];
#pragma unroll
        for (int ks = 0; ks < 2; ++ks)
#pragma unroll
            for (int nb = 0; nb < 4; ++nb)
                kf[ks][nb] = *(const bf16x8*)(kt + nb * 1024 + ks * 512 + fo);
        f32x4 s4[4] = {};
        __builtin_amdgcn_s_setprio(1);
#pragma unroll
        for (int ks = 0; ks < 2; ++ks)
#pragma unroll
            for (int nb = 0; nb < 4; ++nb)
                s4[nb] = __builtin_amdgcn_mfma_f32_16x16x32_bf16(kf[ks][nb], aq[ks],
                                                                 s4[nb], 0, 0, 0);
        __builtin_amdgcn_s_setprio(0);
        bf16x8 vf[2][4];
#pragma unroll
        for (int ks = 0; ks < 2; ++ks)
#pragma unroll
            for (int dnb = 0; dnb < 4; ++dnb)
                vf[ks][dnb] = *(const bf16x8*)(vt + dnb * 1024 + ks * 512 + vo);
        float mn = m;
#pragma unroll
        for (int nb = 0; nb < 4; ++nb)
#pragma unroll
            for (int r = 0; r < 4; ++r) {
                const int j = J0 + nb * 16 + g * 4 + r;
                const int dist = qg - j;
                float xv = s4[nb][r] * SC;
                s4[nb][r] = (dist >= 0 && dist <= wle) ? xv : -__builtin_inff();
                mn = fmaxf(mn, s4[nb][r]);
            }
        mn = fmaxf(mn, __shfl_xor(mn, 16));
        mn = fmaxf(mn, __shfl_xor(mn, 32));
        const float al = exp2f(m - mn);
        m = mn;
        float la = 0.f;
#pragma unroll
        for (int nb = 0; nb < 4; ++nb)
#pragma unroll
            for (int r = 0; r < 4; ++r) {
                float pv = exp2f(s4[nb][r] - m);
                s4[nb][r] = pv;
                la += pv;
            }
        la += __shfl_xor(la, 16);
        la += __shfl_xor(la, 32);
        l = l * al + la;
        float alq[4];
#pragma unroll
        for (int r = 0; r < 4; ++r) alq[r] = __shfl(al, g * 4 + r);
#pragma unroll
        for (int dnb = 0; dnb < 4; ++dnb)
#pragma unroll
            for (int r = 0; r < 4; ++r) o[dnb][r] *= alq[r];
#pragma unroll
        for (int ks = 0; ks < 2; ++ks) {
#pragma unroll
            for (int nb2 = 0; nb2 < 2; ++nb2) {
                const int nb = ks * 2 + nb2;
                bf16x4 pk;
                pk[0] = (bf16_t)s4[nb][0]; pk[1] = (bf16_t)s4[nb][1];
                pk[2] = (bf16_t)s4[nb][2]; pk[3] = (bf16_t)s4[nb][3];
                *reinterpret_cast<bf16x4*>(&pb[w][li][nb2 * 16 + g * 4]) = pk;
            }
            bf16x8 pa = *reinterpret_cast<const bf16x8*>(&pb[w][li][g * 8]);
            __builtin_amdgcn_s_setprio(1);
#pragma unroll
            for (int dnb = 0; dnb < 4; ++dnb)
                o[dnb] = __builtin_amdgcn_mfma_f32_16x16x32_bf16(pa, vf[ks][dnb],
                                                                 o[dnb], 0, 0, 0);
            __builtin_amdgcn_s_setprio(0);
        }
    }

    const float rli = 1.0f / l;
    float rlq[4];
#pragma unroll
    for (int r = 0; r < 4; ++r) rlq[r] = __shfl(rli, g * 4 + r);
#pragma unroll
    for (int dnb = 0; dnb < 4; ++dnb)
#pragma unroll
        for (int r = 0; r < 4; ++r) {
            size_t t = (size_t)qw + g * 4 + r;
            aout[((size_t)b * T_ + t) * C_ + h * 64 + dnb * 16 + li] =
                (bf16_t)(o[dnb][r] * rlq[r]);
        }
}

extern "C" void kernel_launch(void* const* d_in, const int* in_sizes, int n_in,
                              void* d_out, int out_size, void* d_ws, size_t ws_size,
                              hipStream_t stream) {
    const float* x     = (const float*)d_in[0];
    const float* ct    = (const float*)d_in[1];
    const float* st    = (const float*)d_in[2];
    const float* Wqkv  = (const float*)d_in[3];
    const float* Wproj = (const float*)d_in[4];
    const int*   wl    = (const int*)d_in[5];
    float* out = (float*)d_out;
    char* ws = (char*)d_ws;

    bf16_t* wqkvt = (bf16_t*)(ws + (8ull << 20));        // 2 MB  W_qkv^T bf16
    bf16_t* wprot = (bf16_t*)(ws + (10ull << 20));       // 2 MB  W_proj^T bf16
    bf16_t* qp    = (bf16_t*)(ws + (12ull << 20));       // 8 MB  K/Q fragment-packed
    bf16_t* vp    = (bf16_t*)(ws + (20ull << 20));       // 8 MB  V^T fragment-packed
    bf16_t* ao    = (bf16_t*)(ws + (28ull << 20));       // 8 MB  attn out (B,T,C)

    k_prep<<<dim3(2048), dim3(256), 0, stream>>>(Wqkv, wqkvt, Wproj, wprot);
    k_gemm1<<<dim3(512), dim3(256), 0, stream>>>(x, wqkvt, ct, st, qp, vp);
    k_attn<<<dim3(1024), dim3(256), 0, stream>>>(qp, vp, ao, wl);
    k_gemm2<<<dim3(512), dim3(256), 0, stream>>>(ao, wprot, out);
}

// Round 18
// 67.086 us; speedup vs baseline: 1.4123x; 1.4123x over previous
//
#include <hip/hip_runtime.h>
#include <hip/hip_bf16.h>

typedef __bf16 bf16_t;
typedef __bf16 bf16x4 __attribute__((ext_vector_type(4)));
typedef __bf16 bf16x8 __attribute__((ext_vector_type(8)));
typedef float f32x4 __attribute__((ext_vector_type(4)));

#define B_ 2
#define T_ 2048
#define C_ 1024
#define H_ 16
#define HD_ 64
#define RD_ 32
#define M_ (B_ * T_)  // 4096

// ---------------- prep: cvt x fp32->bf16 (blocks 0..4095) + transpose/cvt both W ----------------
__global__ __launch_bounds__(256) void k_prep(const float* __restrict__ x,
                                              bf16_t* __restrict__ xb,
                                              const float* __restrict__ Wq,
                                              bf16_t* __restrict__ wqt,
                                              const float* __restrict__ Wp,
                                              bf16_t* __restrict__ wpt) {
    const int bid = blockIdx.x;
    if (bid < 4096) {
        int i = bid * 256 + threadIdx.x;
        float4 v = reinterpret_cast<const float4*>(x)[i];
        bf16x4 o;
        o[0] = (bf16_t)v.x; o[1] = (bf16_t)v.y; o[2] = (bf16_t)v.z; o[3] = (bf16_t)v.w;
        reinterpret_cast<bf16x4*>(xb)[i] = o;
    } else {
        __shared__ float tile[32][33];
        int b2 = bid - 4096;
        const float* W = (b2 < 1024) ? Wq : Wp;
        bf16_t* Wt = (b2 < 1024) ? wqt : wpt;
        b2 &= 1023;
        const int n0 = (b2 & 31) * 32, k0 = (b2 >> 5) * 32;
        const int tx = threadIdx.x & 31, ty = threadIdx.x >> 5;
        for (int i = ty; i < 32; i += 8)
            tile[i][tx] = W[(size_t)(k0 + i) * C_ + n0 + tx];
        __syncthreads();
        for (int i = ty; i < 32; i += 8)
            Wt[(size_t)(n0 + i) * C_ + k0 + tx] = (bf16_t)tile[tx][i];
    }
}

// ---------------- GEMM: [M][N] = A[M][K]bf16 * Bt[N][K]^T ----------------
// 128x64 tile, BK=64. T3/T4: 3-buffer LDS pipeline, prefetch dist 2, counted
// vmcnt(6) + raw s_barrier per K-step — loads get 2 full steps to land; never
// drain vmcnt to 0 in the main loop. LDS 73.7KB -> 2 blocks/CU, grid 512
// fully resident.
template <bool FUSED>
__global__ __launch_bounds__(256) void k_gemm(const bf16_t* __restrict__ A,
                                              const bf16_t* __restrict__ Bt,
                                              float* __restrict__ C,
                                              const float* __restrict__ ct,
                                              const float* __restrict__ st,
                                              bf16_t* __restrict__ qp,
                                              bf16_t* __restrict__ vp,
                                              int M, int N, int K) {
    __shared__ __align__(16) char smem[73728];   // 3*(128+64)*64*2
    bf16_t* As = (bf16_t*)smem;                  // [3][128*64]
    bf16_t* Bs = (bf16_t*)(smem + 49152);        // [3][64*64]
    const int tid = threadIdx.x;
    const int lane = tid & 63, w = tid >> 6;
    const int wr = w >> 1, wc = w & 1;
    const int g = lane >> 4, li = lane & 15;
    const int bid = blockIdx.x;
    int bx, by;
    if constexpr (FUSED) {
        const int xcd = bid & 7, i = bid >> 3;   // 64 tiles per XCD
        bx = (xcd & 3) * 4 + (i & 3);            // head
        by = (xcd >> 2) * 16 + (i >> 2);         // M block (b*16 + trow)
    } else {
        const int work = (bid & 7) * 64 + (bid >> 3);  // bijective for 512
        bx = work & 15;
        by = work >> 4;
    }
    const size_t rowA0 = (size_t)by * 128;
    const size_t colB0 = (size_t)bx * 64;
    const bf16_t* Ab = A + rowA0 * K;
    const bf16_t* Bb = Bt + colB0 * K;
    f32x4 acc[4][2] = {};

    const int lr = lane >> 3;                 // local row 0..7 per 8-row chunk
    const int swc = ((lane & 7) ^ lr) * 8;    // pre-swizzled source col (elems)

    auto stage = [&](int buf, int k0) {
        bf16_t* Ad = As + buf * 8192 + (w * 8) * 64;
        bf16_t* Bd = Bs + buf * 4096 + (w * 8) * 64;
#pragma unroll
        for (int a = 0; a < 4; ++a) {
            const bf16_t* src = Ab + (size_t)(a * 32 + w * 8 + lr) * K + k0 + swc;
            __builtin_amdgcn_global_load_lds(
                (const __attribute__((address_space(1))) void*)src,
                (__attribute__((address_space(3))) void*)(Ad + a * 32 * 64), 16, 0, 0);
        }
#pragma unroll
        for (int bq = 0; bq < 2; ++bq) {
            const bf16_t* src = Bb + (size_t)(bq * 32 + w * 8 + lr) * K + k0 + swc;
            __builtin_amdgcn_global_load_lds(
                (const __attribute__((address_space(1))) void*)src,
                (__attribute__((address_space(3))) void*)(Bd + bq * 32 * 64), 16, 0, 0);
        }
    };

    const int NT = K >> 6;                    // 16
    stage(0, 0);
    stage(1, 64);
    for (int kt = 0; kt < NT; ++kt) {
        // wait for buf[kt]'s 6 loads (issued 2 steps ago); keep newer in flight
        if (kt + 1 < NT)
            asm volatile("s_waitcnt vmcnt(6)" ::: "memory");
        else
            asm volatile("s_waitcnt vmcnt(0)" ::: "memory");
        __builtin_amdgcn_s_barrier();         // publish staged LDS to all waves
        if (kt + 2 < NT) stage((kt + 2) % 3, (kt + 2) << 6);
        const int cb = kt % 3;
        bf16x8 af[4][2], bfr[2][2];
#pragma unroll
        for (int i = 0; i < 4; ++i) {
            const int row = wr * 64 + i * 16 + li;
#pragma unroll
            for (int kk = 0; kk < 2; ++kk)
                af[i][kk] = *(const bf16x8*)(As + cb * 8192 + row * 64 +
                                             (((kk * 4 + g) ^ (li & 7)) * 8));
        }
#pragma unroll
        for (int j = 0; j < 2; ++j) {
            const int row = wc * 32 + j * 16 + li;
#pragma unroll
            for (int kk = 0; kk < 2; ++kk)
                bfr[j][kk] = *(const bf16x8*)(Bs + cb * 4096 + row * 64 +
                                              (((kk * 4 + g) ^ (li & 7)) * 8));
        }
#pragma unroll
        for (int i = 0; i < 4; ++i)
#pragma unroll
            for (int j = 0; j < 2; ++j)
#pragma unroll
                for (int kk = 0; kk < 2; ++kk)
                    acc[i][j] = __builtin_amdgcn_mfma_f32_16x16x32_bf16(
                        af[i][kk], bfr[j][kk], acc[i][j], 0, 0, 0);
        // no end-of-step barrier: next step's vmcnt+barrier covers it.
    }

    if constexpr (!FUSED) {
#pragma unroll
        for (int i = 0; i < 4; ++i)
#pragma unroll
            for (int j = 0; j < 2; ++j)
#pragma unroll
                for (int r = 0; r < 4; ++r) {
                    size_t row = rowA0 + wr * 64 + i * 16 + g * 4 + r;
                    size_t col = colB0 + wc * 32 + j * 16 + li;
                    C[row * N + col] = acc[i][j][r];
                }
    } else {
        __syncthreads();   // all waves done reading LDS before smem reuse
        // ---- fused RoPE + RMS epilogue (head = bx, 128 t-rows in one b) ----
        float* ot = (float*)smem;                   // [128][68] fp32
        bf16_t* qs = (bf16_t*)(smem + 34816);       // [64][136] bf16 (d-major)
#pragma unroll
        for (int i = 0; i < 4; ++i)
#pragma unroll
            for (int j = 0; j < 2; ++j)
#pragma unroll
                for (int r = 0; r < 4; ++r)
                    ot[(wr * 64 + i * 16 + g * 4 + r) * 68 + wc * 32 + j * 16 + li] =
                        acc[i][j][r];
        __syncthreads();
        const int bb = (int)(rowA0 >> 11);
        {
            const int row = tid >> 1, half = tid & 1;  // 2 threads per t-row
            const int t = ((int)rowA0 + row) & 2047;
            const float* own = ot + row * 68 + half * 32;
            const float* par = ot + row * 68 + (half ^ 1) * 32;
            const float* cp = ct + (size_t)t * RD_;
            const float* sp = st + (size_t)t * RD_;
            float y[32];
            float sq = 0.f;
#pragma unroll
            for (int c4 = 0; c4 < 8; ++c4) {
                float4 xo = ((const float4*)own)[c4];
                float4 xp = ((const float4*)par)[c4];
                float4 cc = ((const float4*)cp)[c4];
                float4 ss = ((const float4*)sp)[c4];
                float* yy = y + c4 * 4;
                if (half == 0) {
                    yy[0] = xo.x * cc.x + xp.x * ss.x;
                    yy[1] = xo.y * cc.y + xp.y * ss.y;
                    yy[2] = xo.z * cc.z + xp.z * ss.z;
                    yy[3] = xo.w * cc.w + xp.w * ss.w;
                } else {
                    yy[0] = xo.x * cc.x - xp.x * ss.x;
                    yy[1] = xo.y * cc.y - xp.y * ss.y;
                    yy[2] = xo.z * cc.z - xp.z * ss.z;
                    yy[3] = xo.w * cc.w - xp.w * ss.w;
                }
                sq += yy[0] * yy[0] + yy[1] * yy[1] + yy[2] * yy[2] + yy[3] * yy[3];
            }
            sq += __shfl_xor(sq, 1);
            const float rn = rsqrtf(sq * (1.0f / 64.0f) + 1.1920929e-7f);
            bf16_t yb[32];
#pragma unroll
            for (int e = 0; e < 32; ++e) yb[e] = (bf16_t)(y[e] * rn);
            // K/Q-packed write: group t>>4, chunk (d>>3)*16 + (t&15)
            bf16_t* qpb = qp + ((size_t)(bb * H_ + bx) * 128 + (t >> 4)) * 1024;
#pragma unroll
            for (int c8 = 0; c8 < 4; ++c8) {
                const int chunk = (half * 4 + c8) * 16 + (t & 15);
                *(bf16x8*)(qpb + chunk * 8) = *(const bf16x8*)(yb + c8 * 8);
            }
            // also stash d-major in LDS for the V-pack pass
#pragma unroll
            for (int e = 0; e < 32; ++e)
                qs[(half * 32 + e) * 136 + row] = yb[e];
        }
        __syncthreads();
        {
            // V^T-packed write: 2 tiles of 64 keys in this block's 128 rows
            const int d = tid >> 2, jc4 = tid & 3;
            const int tt0 = (int)((rowA0 & 2047) >> 6);
            bf16_t* vpb = vp + ((size_t)(bb * H_ + bx) * 32) * 4096;
#pragma unroll
            for (int c = 0; c < 4; ++c) {
                const int jc = jc4 * 4 + c;               // 0..15 (j-chunk of 8)
                bf16x8 v8 = *(const bf16x8*)(qs + d * 136 + jc * 8);
                bf16_t* dst = vpb + (size_t)(tt0 + (jc >> 3)) * 4096 +
                              ((d >> 4) * 8 + (jc & 7)) * 128 + (d & 15) * 8;
                *(bf16x8*)dst = v8;
            }
        }
    }
}

// ---------------- flash attention (round-12 structure; best measured) ----------------
__global__ __launch_bounds__(256, 2) void k_attn(const bf16_t* __restrict__ qp,
                                                 const bf16_t* __restrict__ vp,
                                                 bf16_t* __restrict__ aout,
                                                 const int* __restrict__ wlp) {
    __shared__ bf16_t pb[4][16][40];   // per-wave P half-tile [q][32 keys + pad]
    const int tid = threadIdx.x;
    const int lane = tid & 63, w = tid >> 6;
    const int g = lane >> 4, li = lane & 15;
    const int bid = blockIdx.x;
    const int work = (bid & 7) * 128 + (bid >> 3);  // bijective for 1024 blocks
    const int tb = work & 31;
    const int h = (work >> 5) & 15;
    const int b = work >> 9;
    const int Q0 = tb * 64;
    const bf16_t* bq = qp + (size_t)(b * H_ + h) * 131072;
    const bf16_t* bv = vp + (size_t)(b * H_ + h) * 131072;
    const int wl = wlp[0];
    const int wle = (wl <= 0 || wl > T_) ? T_ : wl;
    const int qw = Q0 + w * 16;
    const int qg = qw + li;            // this lane's query (softmax phase)

    const int fo = (g * 16 + li) * 8;  // K/Q fragment lane offset (+ks*512)
    const int vo = g * 128 + li * 8;   // V fragment lane offset (+ks*512)

    bf16x8 aq[2];
    aq[0] = *(const bf16x8*)(bq + (size_t)(qw >> 4) * 1024 + fo);
    aq[1] = *(const bf16x8*)(bq + (size_t)(qw >> 4) * 1024 + fo + 512);

    f32x4 o[4] = {};
    float m = -1e30f, l = 0.f;
    const float SC = 0.125f * 1.44269504089f;  // HD^-0.5 * log2(e)

    const int kb0 = (qw > wle) ? ((qw - wle) >> 6) : 0;   // per-wave range
    const int kb1 = qw >> 6;

    for (int kb = kb0; kb <= kb1; ++kb) {
        const int J0 = kb << 6;
        const bf16_t* kt = bq + (size_t)kb * 4096;
        const bf16_t* vt = bv + (size_t)kb * 4096;
        bf16x8 kf[2][4];
#pragma unroll
        for (int ks = 0; ks < 2; ++ks)
#pragma unroll
            for (int nb = 0; nb < 4; ++nb)
                kf[ks][nb] = *(const bf16x8*)(kt + nb * 1024 + ks * 512 + fo);
        f32x4 s4[4] = {};
        __builtin_amdgcn_s_setprio(1);
#pragma unroll
        for (int ks = 0; ks < 2; ++ks)
#pragma unroll
            for (int nb = 0; nb < 4; ++nb)
                s4[nb] = __builtin_amdgcn_mfma_f32_16x16x32_bf16(kf[ks][nb], aq[ks],
                                                                 s4[nb], 0, 0, 0);
        __builtin_amdgcn_s_setprio(0);
        bf16x8 vf[2][4];
#pragma unroll
        for (int ks = 0; ks < 2; ++ks)
#pragma unroll
            for (int dnb = 0; dnb < 4; ++dnb)
                vf[ks][dnb] = *(const bf16x8*)(vt + dnb * 1024 + ks * 512 + vo);
        float mn = m;
#pragma unroll
        for (int nb = 0; nb < 4; ++nb)
#pragma unroll
            for (int r = 0; r < 4; ++r) {
                const int j = J0 + nb * 16 + g * 4 + r;
                const int dist = qg - j;
                float xv = s4[nb][r] * SC;
                s4[nb][r] = (dist >= 0 && dist <= wle) ? xv : -__builtin_inff();
                mn = fmaxf(mn, s4[nb][r]);
            }
        mn = fmaxf(mn, __shfl_xor(mn, 16));
        mn = fmaxf(mn, __shfl_xor(mn, 32));
        const float al = exp2f(m - mn);
        m = mn;
        float la = 0.f;
#pragma unroll
        for (int nb = 0; nb < 4; ++nb)
#pragma unroll
            for (int r = 0; r < 4; ++r) {
                float pv = exp2f(s4[nb][r] - m);  // exp2(-inf) = 0
                s4[nb][r] = pv;
                la += pv;
            }
        la += __shfl_xor(la, 16);
        la += __shfl_xor(la, 32);
        l = l * al + la;
        float alq[4];
#pragma unroll
        for (int r = 0; r < 4; ++r) alq[r] = __shfl(al, g * 4 + r);
#pragma unroll
        for (int dnb = 0; dnb < 4; ++dnb)
#pragma unroll
            for (int r = 0; r < 4; ++r) o[dnb][r] *= alq[r];
#pragma unroll
        for (int ks = 0; ks < 2; ++ks) {
#pragma unroll
            for (int nb2 = 0; nb2 < 2; ++nb2) {
                const int nb = ks * 2 + nb2;
                bf16x4 pk;
                pk[0] = (bf16_t)s4[nb][0]; pk[1] = (bf16_t)s4[nb][1];
                pk[2] = (bf16_t)s4[nb][2]; pk[3] = (bf16_t)s4[nb][3];
                *reinterpret_cast<bf16x4*>(&pb[w][li][nb2 * 16 + g * 4]) = pk;
            }
            bf16x8 pa = *reinterpret_cast<const bf16x8*>(&pb[w][li][g * 8]);
            __builtin_amdgcn_s_setprio(1);
#pragma unroll
            for (int dnb = 0; dnb < 4; ++dnb)
                o[dnb] = __builtin_amdgcn_mfma_f32_16x16x32_bf16(pa, vf[ks][dnb],
                                                                 o[dnb], 0, 0, 0);
            __builtin_amdgcn_s_setprio(0);
        }
    }

    const float rli = 1.0f / l;
    float rlq[4];
#pragma unroll
    for (int r = 0; r < 4; ++r) rlq[r] = __shfl(rli, g * 4 + r);
#pragma unroll
    for (int dnb = 0; dnb < 4; ++dnb)
#pragma unroll
        for (int r = 0; r < 4; ++r) {
            size_t t = (size_t)qw + g * 4 + r;
            aout[((size_t)b * T_ + t) * C_ + h * 64 + dnb * 16 + li] =
                (bf16_t)(o[dnb][r] * rlq[r]);
        }
}

extern "C" void kernel_launch(void* const* d_in, const int* in_sizes, int n_in,
                              void* d_out, int out_size, void* d_ws, size_t ws_size,
                              hipStream_t stream) {
    const float* x     = (const float*)d_in[0];
    const float* ct    = (const float*)d_in[1];
    const float* st    = (const float*)d_in[2];
    const float* Wqkv  = (const float*)d_in[3];
    const float* Wproj = (const float*)d_in[4];
    const int*   wl    = (const int*)d_in[5];
    float* out = (float*)d_out;
    char* ws = (char*)d_ws;

    bf16_t* xb    = (bf16_t*)(ws);                       // 8 MB  x in bf16
    bf16_t* wqkvt = (bf16_t*)(ws + (8ull << 20));        // 2 MB  W_qkv^T bf16
    bf16_t* wprot = (bf16_t*)(ws + (10ull << 20));       // 2 MB  W_proj^T bf16
    bf16_t* qp    = (bf16_t*)(ws + (12ull << 20));       // 8 MB  K/Q fragment-packed
    bf16_t* vp    = (bf16_t*)(ws + (20ull << 20));       // 8 MB  V^T fragment-packed
    bf16_t* ao    = (bf16_t*)(ws + (28ull << 20));       // 8 MB  attn out (B,T,C)

    k_prep<<<dim3(6144), dim3(256), 0, stream>>>(x, xb, Wqkv, wqkvt, Wproj, wprot);
    k_gemm<true><<<dim3(512), dim3(256), 0, stream>>>(xb, wqkvt, nullptr, ct, st,
                                                      qp, vp, M_, C_, C_);
    k_attn<<<dim3(1024), dim3(256), 0, stream>>>(qp, vp, ao, wl);
    k_gemm<false><<<dim3(512), dim3(256), 0, stream>>>(ao, wprot, out, nullptr, nullptr,
                                                       nullptr, nullptr, M_, C_, C_);
}